// Round 7
// baseline (100.489 us; speedup 1.0000x reference)
//
#include <hip/hip_runtime.h>
#include <hip/hip_bf16.h>
#include <type_traits>

#define NB 8192
#define DD 256
#define INV_T (1.0f/0.07f)
#define LOG2E 1.4426950408889634f
#define K1    (INV_T*LOG2E)          // logit (log2 units) = acc*K1 - K1
#define CEXP  6.2087204553847255e-7f // exp(-1/0.07): folds the -K1 term into se
#define NSPLIT 8
#define BM 256
#define BN 64
#define CPS (NB/NSPLIT)      // 1024 cols per split
#define NITER (CPS/BN)       // 16
#define BUFB (BN*DD*2)       // 32768 bytes per LDS buffer

typedef __attribute__((ext_vector_type(8))) short s8v;   // 8 bf16
typedef __attribute__((ext_vector_type(4))) float f4v;   // 4 f32 acc
typedef unsigned int u32;
typedef unsigned short u16;

// workspace layout (bytes)
#define OFF_FB   0                                  // bf16 normalized features: 4 MB
#define OFF_SE   (4*1024*1024)                      // f32 [NSPLIT][NB]
#define OFF_SP   (OFF_SE + NSPLIT*NB*4)
#define OFF_CL   (OFF_SP + NSPLIT*NB*4)             // f32[32]
#define OFF_CV   (OFF_CL + 256)                     // f32[32]
#define OFF_CNT  (OFF_CV + 256)                     // int[1]

// wave-per-row normalize: grid 2048 x 256 threads; block 0 zeros the finish counter
__global__ void k_norm(const float* __restrict__ feat,
                       __hip_bfloat16* __restrict__ fb, int* __restrict__ cnt) {
    if (blockIdx.x == 0 && threadIdx.x == 0) *cnt = 0;
    const int t = threadIdx.x;
    const int w = t >> 6, l = t & 63;
    const int row = blockIdx.x * 4 + w;
    const float4 v = ((const float4*)feat)[row * 64 + l];
    float s = v.x * v.x + v.y * v.y + v.z * v.z + v.w * v.w;
    #pragma unroll
    for (int d = 32; d; d >>= 1) s += __shfl_xor(s, d, 64);
    const float scale = 1.0f / fmaxf(sqrtf(s), 1e-12f);
    __hip_bfloat16 h0 = __float2bfloat16(v.x * scale);
    __hip_bfloat16 h1 = __float2bfloat16(v.y * scale);
    __hip_bfloat16 h2 = __float2bfloat16(v.z * scale);
    __hip_bfloat16 h3 = __float2bfloat16(v.w * scale);
    ushort4 o;
    o.x = *(u16*)&h0; o.y = *(u16*)&h1; o.z = *(u16*)&h2; o.w = *(u16*)&h3;
    ((ushort4*)fb)[row * 64 + l] = o;
}

__device__ __forceinline__ void gld16(const void* g, void* l) {
    __builtin_amdgcn_global_load_lds((const __attribute__((address_space(1))) u32*)g,
                                     (__attribute__((address_space(3))) u32*)l, 16, 0, 0);
}

// fused sim + row-reduction. grid 256 linear; sp = bid&7 (XCD affinity), rb = bid>>3.
// block 512 thr = 8 waves as 4 wm x 2 wn; wave owns 64 rows x 32 cols of each tile.
// n-split halves per-CU LDS-read volume (2 waves per column instead of 8).
// B staged via global_load_lds (L2-resident source, inverse-swizzled addresses).
__launch_bounds__(512, 2)
__global__ void k_main(const __hip_bfloat16* __restrict__ fb,
                       const int* __restrict__ lab,
                       float* __restrict__ SE, float* __restrict__ SP) {
    __shared__ __align__(16) char ldsB[2 * BUFB];  // 64 KB, XOR-swizzled
    __shared__ int ldsLab[CPS];                    // 4 KB col labels
    __shared__ float ldsRE[2][BM];                 // 2 KB wn-combine (exp sums)
    __shared__ float ldsRP[2][BM];                 // 2 KB wn-combine (pos sums)
    const int tid = threadIdx.x;
    const int w = tid >> 6;
    const int l = tid & 63;
    const int l15 = l & 15, lg = l >> 4;
    const int wm = w >> 1, wn = w & 1;
    const int bid = blockIdx.x;
    const int sp = bid & 7, rb = bid >> 3;
    const int row0 = rb * BM;
    const int wbase = row0 + wm * 64;
    const int col0 = sp * CPS;

    // stage this split's column labels once
    ldsLab[tid]       = lab[col0 + tid];
    ldsLab[tid + 512] = lab[col0 + 512 + tid];

    // A fragments in registers: rows wbase + m*16 + l15, k = kk*32 + lg*8 + [0..7]
    s8v a[4][8];
    #pragma unroll
    for (int m = 0; m < 4; m++)
        #pragma unroll
        for (int kk = 0; kk < 8; kk++)
            a[m][kk] = *(const s8v*)(fb + (wbase + m * 16 + l15) * DD + kk * 32 + lg * 8);

    // labels of the 16 rows this lane accumulates
    int labr[16];
    #pragma unroll
    for (int m = 0; m < 4; m++)
        #pragma unroll
        for (int r = 0; r < 4; r++)
            labr[m * 4 + r] = lab[wbase + m * 16 + lg * 4 + r];

    float sE[16], sPa[16];
    #pragma unroll
    for (int i = 0; i < 16; i++) { sE[i] = 0.f; sPa[i] = 0.f; }

    // stage a 64x256 bf16 tile (32 KB) via global_load_lds:
    // linear LDS dest, inverse-swizzled global source (rule: both-sides-or-neither)
    auto stage = [&](int t, int bufoff) {
        const char* gt = (const char*)fb + (size_t)(col0 + t * BN) * (DD * 2);
        #pragma unroll
        for (int i = 0; i < 4; i++) {
            const int x = i * 8192 + w * 1024 + (l << 4);   // linear LDS byte offset
            const int br = x >> 9;
            const int inrow = x & 511;
            gld16(gt + br * 512 + (inrow ^ ((br & 7) << 4)),
                  ldsB + bufoff + i * 8192 + w * 1024);
        }
    };

    auto run = [&](auto diagC) {
        constexpr bool DIAG = decltype(diagC)::value;
        stage(0, 0);
        __syncthreads();
        for (int t = 0; t < NITER; t++) {
            const int curoff = (t & 1) * BUFB;
            if (t + 1 < NITER) stage(t + 1, curoff ^ BUFB);

            const int lc0 = ldsLab[t * BN + wn * 32 + l15];
            const int lc1 = ldsLab[t * BN + wn * 32 + 16 + l15];

            f4v acc[4][2];
            #pragma unroll
            for (int m = 0; m < 4; m++) {
                acc[m][0] = (f4v){0.f, 0.f, 0.f, 0.f};
                acc[m][1] = (f4v){0.f, 0.f, 0.f, 0.f};
            }

            #pragma unroll
            for (int kk = 0; kk < 8; kk++) {
                const int br0 = wn * 32 + l15;
                const int br1 = wn * 32 + 16 + l15;
                s8v b0 = *(const s8v*)(ldsB + curoff + ((br0 * 512 + kk * 64 + lg * 16) ^ ((br0 & 7) << 4)));
                s8v b1 = *(const s8v*)(ldsB + curoff + ((br1 * 512 + kk * 64 + lg * 16) ^ ((br1 & 7) << 4)));
                #pragma unroll
                for (int m = 0; m < 4; m++)
                    acc[m][0] = __builtin_amdgcn_mfma_f32_16x16x32_bf16(a[m][kk], b0, acc[m][0], 0, 0, 0);
                #pragma unroll
                for (int m = 0; m < 4; m++)
                    acc[m][1] = __builtin_amdgcn_mfma_f32_16x16x32_bf16(a[m][kk], b1, acc[m][1], 0, 0, 0);
            }

            const int cb = col0 + t * BN;
            #pragma unroll
            for (int n = 0; n < 2; n++) {
                const int lcn = n ? lc1 : lc0;
                const int coln = cb + wn * 32 + n * 16 + l15;
                #pragma unroll
                for (int m = 0; m < 4; m++)
                    #pragma unroll
                    for (int r = 0; r < 4; r++) {
                        const int idx = m * 4 + r;
                        const float v = acc[m][n][r];
                        float e = exp2f(v * K1);          // unscaled: true e = CEXP * this
                        bool pos = (lcn == labr[idx]);
                        if (DIAG) {
                            const int row = wbase + m * 16 + lg * 4 + r;
                            const bool nself = (row != coln);
                            e = nself ? e : 0.f;
                            pos = pos && nself;
                        }
                        sE[idx] += e;
                        sPa[idx] += pos ? v : 0.f;        // raw sim; log-term folded in k_rows
                    }
            }

            __syncthreads();
        }
    };
    if ((rb >> 2) == sp) run(std::true_type{}); else run(std::false_type{});

    // reduce across the 16 lanes of each group
    #pragma unroll
    for (int idx = 0; idx < 16; idx++) {
        #pragma unroll
        for (int d = 1; d < 16; d <<= 1) {
            sE[idx]  += __shfl_xor(sE[idx], d, 16);
            sPa[idx] += __shfl_xor(sPa[idx], d, 16);
        }
    }
    if (l15 == 0) {
        #pragma unroll
        for (int idx = 0; idx < 16; idx++) {
            const int rowl = wm * 64 + (idx >> 2) * 16 + lg * 4 + (idx & 3);
            ldsRE[wn][rowl] = sE[idx];
            ldsRP[wn][rowl] = sPa[idx];
        }
    }
    __syncthreads();
    {
        const int r = tid & 255;
        if (tid < 256) SE[sp * NB + row0 + r] = ldsRE[0][r] + ldsRE[1][r];
        else           SP[sp * NB + row0 + r] = ldsRP[0][r] + ldsRP[1][r];
    }
}

// per-row finalize; 32 blocks of 256 (one 256-row chunk each).
// loss_row = log(se*CEXP + 1e-8) - (spa - n)*INV_T/n   [spa = sum_pos sim]
// Chunk fallback provably dead: CHUNK=256 > NUM_CLASSES=128.
__global__ void k_rows(const int* __restrict__ lab,
                       const float* __restrict__ SE, const float* __restrict__ SP,
                       float* __restrict__ CL, float* __restrict__ CV,
                       int* __restrict__ cnt, float* __restrict__ out) {
    __shared__ int h[128];
    const int t = threadIdx.x;
    if (t < 128) h[t] = 0;
    __syncthreads();
    #pragma unroll
    for (int i = 0; i < 32; i++)
        atomicAdd(&h[lab[t + i * 256]], 1);
    __syncthreads();

    const int row = blockIdx.x * 256 + t;
    float se = 0.f, spa = 0.f;
    #pragma unroll
    for (int s = 0; s < NSPLIT; s++) {
        se  += SE[s * NB + row];
        spa += SP[s * NB + row];
    }
    const int n = h[lab[row]] - 1;
    const float lse = logf(se * CEXP + 1e-8f);
    const bool valid = n > 0;
    float loss = valid ? (lse - (spa - (float)n) * INV_T / (float)n) : 0.f;
    float vf = valid ? 1.f : 0.f;
    #pragma unroll
    for (int d = 32; d; d >>= 1) { loss += __shfl_xor(loss, d, 64); vf += __shfl_xor(vf, d, 64); }
    __shared__ float pl[4], pv[4];
    __shared__ int isLast;
    if ((t & 63) == 0) { pl[t >> 6] = loss; pv[t >> 6] = vf; }
    __syncthreads();
    if (t == 0) {
        CL[blockIdx.x] = pl[0] + pl[1] + pl[2] + pl[3];
        CV[blockIdx.x] = pv[0] + pv[1] + pv[2] + pv[3];
        __threadfence();                       // release CL/CV
        isLast = (atomicAdd(cnt, 1) == 31);
    }
    __syncthreads();
    if (isLast) {
        __threadfence();                       // acquire others' CL/CV
        float lsum = (t < 32) ? CL[t] : 0.f;
        float vsum = (t < 32) ? CV[t] : 0.f;
        #pragma unroll
        for (int d = 32; d; d >>= 1) { lsum += __shfl_xor(lsum, d, 64); vsum += __shfl_xor(vsum, d, 64); }
        if (t == 0) {
            const float mean = lsum / (vsum + 1e-8f);
            out[0] = mean;   // loss (reduction == 'mean')
            out[1] = vsum;   // total_pairs
            out[2] = mean;   // mean_loss
        }
    }
}

extern "C" void kernel_launch(void* const* d_in, const int* in_sizes, int n_in,
                              void* d_out, int out_size, void* d_ws, size_t ws_size,
                              hipStream_t stream) {
    (void)in_sizes; (void)n_in; (void)out_size; (void)ws_size;
    const float* feat = (const float*)d_in[0];
    const int*   lab  = (const int*)d_in[1];
    char* ws = (char*)d_ws;
    __hip_bfloat16* fb = (__hip_bfloat16*)(ws + OFF_FB);
    float* SE = (float*)(ws + OFF_SE);
    float* SP = (float*)(ws + OFF_SP);
    float* CL = (float*)(ws + OFF_CL);
    float* CV = (float*)(ws + OFF_CV);
    int*   cnt = (int*)(ws + OFF_CNT);
    float* out = (float*)d_out;

    hipLaunchKernelGGL(k_norm, dim3(NB / 4), dim3(256), 0, stream, feat, fb, cnt);
    hipLaunchKernelGGL(k_main, dim3(NB / BM * NSPLIT), dim3(512), 0, stream, fb, lab, SE, SP);
    hipLaunchKernelGGL(k_rows, dim3(NB / 256), dim3(256), 0, stream, lab, SE, SP, CL, CV, cnt, out);
}

// Round 8
// 74.221 us; speedup vs baseline: 1.3539x; 1.3539x over previous
//
#include <hip/hip_runtime.h>
#include <hip/hip_bf16.h>
#include <type_traits>

#define NB 8192
#define DD 256
#define INV_T (1.0f/0.07f)
#define LOG2E 1.4426950408889634f
#define K1    (INV_T*LOG2E)          // logit (log2 units) = acc*K1 - K1
#define CEXP  6.2087204553847255e-7f // exp(-1/0.07): folds the -K1 term into se
#define NSTRIP 32
#define TILE 256
#define BN 64
#define NITER 4              // 256 cols / 64
#define BUFB (BN*DD*2)       // 32768 bytes per LDS buffer

typedef __attribute__((ext_vector_type(8))) short s8v;   // 8 bf16
typedef __attribute__((ext_vector_type(4))) float f4v;   // 4 f32 acc
typedef unsigned int u32;
typedef unsigned short u16;

// workspace layout (bytes)  (total ~6.2 MB)
#define OFF_FB   0                                  // bf16 normalized features: 4 MB
#define OFF_SE   (4*1024*1024)                      // f32 [32][8192] = 1 MB
#define OFF_SP   (OFF_SE + NSTRIP*NB*4)             // f32 [32][8192] = 1 MB
#define OFF_CL   (OFF_SP + NSTRIP*NB*4)             // f32[32]
#define OFF_CV   (OFF_CL + 256)                     // f32[32]
#define OFF_CNT  (OFF_CV + 256)                     // int[1]

// wave-per-row normalize: grid 2048 x 256 threads; block 0 zeros the finish counter
__global__ void k_norm(const float* __restrict__ feat,
                       __hip_bfloat16* __restrict__ fb, int* __restrict__ cnt) {
    if (blockIdx.x == 0 && threadIdx.x == 0) *cnt = 0;
    const int t = threadIdx.x;
    const int w = t >> 6, l = t & 63;
    const int row = blockIdx.x * 4 + w;
    const float4 v = ((const float4*)feat)[row * 64 + l];
    float s = v.x * v.x + v.y * v.y + v.z * v.z + v.w * v.w;
    #pragma unroll
    for (int d = 32; d; d >>= 1) s += __shfl_xor(s, d, 64);
    const float scale = 1.0f / fmaxf(sqrtf(s), 1e-12f);
    __hip_bfloat16 h0 = __float2bfloat16(v.x * scale);
    __hip_bfloat16 h1 = __float2bfloat16(v.y * scale);
    __hip_bfloat16 h2 = __float2bfloat16(v.z * scale);
    __hip_bfloat16 h3 = __float2bfloat16(v.w * scale);
    ushort4 o;
    o.x = *(u16*)&h0; o.y = *(u16*)&h1; o.z = *(u16*)&h2; o.w = *(u16*)&h3;
    ((ushort4*)fb)[row * 64 + l] = o;
}

// Symmetric fused sim + row/col reduction.
// Grid = 528 = lower-triangle 256x256 tiles (rb >= cb), cb-major.
// Off-diagonal tile computed ONCE: row-sums -> strip[cb][rows of rb],
// col-sums -> strip[rb][cols of cb]. Diagonal: self-masked, row-sums only.
// Slot [k][i] (m=i>>8): k<m from tile(m,k) rows; k>m from tile(k,m) cols;
// k==m diagonal. Bijective -> no atomics.
__launch_bounds__(512)
__global__ void k_main(const __hip_bfloat16* __restrict__ fb,
                       const int* __restrict__ lab,
                       float* __restrict__ SE, float* __restrict__ SP) {
    __shared__ __align__(16) char ldsB[2 * BUFB];   // 64 KB, XOR-swizzled
    __shared__ int ldsLab[TILE];                    // 1 KB col labels
    __shared__ float ldsColE[8][TILE];              // 8 KB per-wave col sums
    __shared__ float ldsColP[8][TILE];              // 8 KB
    const int tid = threadIdx.x;
    const int w = tid >> 6;
    const int l = tid & 63;
    const int l15 = l & 15, lg = l >> 4;

    // decode bid -> (rb, cb), cb-major lower triangle
    int cb = 0, rem = blockIdx.x;
    while (rem >= NSTRIP - cb) { rem -= NSTRIP - cb; cb++; }
    const int rb = cb + rem;
    const int row0 = rb * TILE, col0 = cb * TILE;
    const int wbase = row0 + w * 32;

    if (tid < TILE) ldsLab[tid] = lab[col0 + tid];

    // A fragments in registers: rows wbase + m*16 + l15, k = kk*32 + lg*8 + [0..7]
    s8v a[2][8];
    #pragma unroll
    for (int m = 0; m < 2; m++)
        #pragma unroll
        for (int kk = 0; kk < 8; kk++)
            a[m][kk] = *(const s8v*)(fb + (wbase + m * 16 + l15) * DD + kk * 32 + lg * 8);

    // labels of the 8 rows this lane accumulates
    int labr[8];
    #pragma unroll
    for (int m = 0; m < 2; m++)
        #pragma unroll
        for (int r = 0; r < 4; r++)
            labr[m * 4 + r] = lab[wbase + m * 16 + lg * 4 + r];

    float sE[8], sPa[8], colE[4], colP[4];
    #pragma unroll
    for (int i = 0; i < 8; i++) { sE[i] = 0.f; sPa[i] = 0.f; }
    #pragma unroll
    for (int i = 0; i < 4; i++) { colE[i] = 0.f; colP[i] = 0.f; }

    // staging: lane-contiguous global load (coalesced), swizzled ds_write (R4-proven)
    s8v st[4];
    auto load_tile = [&](int ct) {
        const char* gsrc = (const char*)fb + (size_t)(col0 + ct * BN) * (DD * 2);
        #pragma unroll
        for (int i = 0; i < 4; i++)
            st[i] = *(const s8v*)(gsrc + tid * 16 + i * 8192);
    };
    auto write_tile = [&](int bufoff) {
        #pragma unroll
        for (int i = 0; i < 4; i++) {
            const int x = tid * 16 + i * 8192;
            const int br = x >> 9, inrow = x & 511;
            *(s8v*)(ldsB + bufoff + (br * 512 | (inrow ^ ((br & 7) << 4)))) = st[i];
        }
    };

    auto run = [&](auto diagC) {
        constexpr bool DIAG = decltype(diagC)::value;
        load_tile(0);
        write_tile(0);
        __syncthreads();
        for (int ct = 0; ct < NITER; ct++) {
            const int curoff = (ct & 1) * BUFB;
            if (ct + 1 < NITER) load_tile(ct + 1);

            int lc[4];
            #pragma unroll
            for (int n = 0; n < 4; n++)
                lc[n] = ldsLab[ct * BN + n * 16 + l15];

            f4v acc[2][4];
            #pragma unroll
            for (int m = 0; m < 2; m++)
                #pragma unroll
                for (int n = 0; n < 4; n++)
                    acc[m][n] = (f4v){0.f, 0.f, 0.f, 0.f};

            #pragma unroll
            for (int kk = 0; kk < 8; kk++) {
                s8v bfr[4];
                #pragma unroll
                for (int n = 0; n < 4; n++) {
                    const int br = n * 16 + l15;
                    const int ad = (br * 512 + kk * 64 + lg * 16) ^ ((br & 7) << 4);
                    bfr[n] = *(const s8v*)(ldsB + curoff + ad);
                }
                #pragma unroll
                for (int m = 0; m < 2; m++)
                    #pragma unroll
                    for (int n = 0; n < 4; n++)
                        acc[m][n] = __builtin_amdgcn_mfma_f32_16x16x32_bf16(a[m][kk], bfr[n], acc[m][n], 0, 0, 0);
            }

            #pragma unroll
            for (int n = 0; n < 4; n++) {
                #pragma unroll
                for (int m = 0; m < 2; m++)
                    #pragma unroll
                    for (int r = 0; r < 4; r++) {
                        const int idx = m * 4 + r;
                        const float v = acc[m][n][r];
                        float e = exp2f(v * K1);          // true e = CEXP * this
                        bool pos = (lc[n] == labr[idx]);
                        if (DIAG) {
                            const int row = wbase + m * 16 + lg * 4 + r;
                            const int coln = col0 + ct * BN + n * 16 + l15;
                            const bool nself = (row != coln);
                            e = nself ? e : 0.f;
                            pos = pos && nself;
                        }
                        const float pv = pos ? v : 0.f;
                        sE[idx] += e;
                        sPa[idx] += pv;
                        if (!DIAG) { colE[n] += e; colP[n] += pv; }
                    }
            }

            if (!DIAG) {
                // reduce col sums across the 4 lg groups; stage per wave
                #pragma unroll
                for (int n = 0; n < 4; n++) {
                    colE[n] += __shfl_xor(colE[n], 16, 64);
                    colE[n] += __shfl_xor(colE[n], 32, 64);
                    colP[n] += __shfl_xor(colP[n], 16, 64);
                    colP[n] += __shfl_xor(colP[n], 32, 64);
                }
                if (l < 16) {
                    #pragma unroll
                    for (int n = 0; n < 4; n++) {
                        ldsColE[w][ct * BN + n * 16 + l15] = colE[n];
                        ldsColP[w][ct * BN + n * 16 + l15] = colP[n];
                    }
                }
                #pragma unroll
                for (int n = 0; n < 4; n++) { colE[n] = 0.f; colP[n] = 0.f; }
            }

            if (ct + 1 < NITER) write_tile(curoff ^ BUFB);
            __syncthreads();
        }
    };
    if (rb == cb) run(std::true_type{}); else run(std::false_type{});

    // row-sums: reduce across the 16 lanes of each group -> strip[cb]
    #pragma unroll
    for (int idx = 0; idx < 8; idx++) {
        #pragma unroll
        for (int d = 1; d < 16; d <<= 1) {
            sE[idx]  += __shfl_xor(sE[idx], d, 16);
            sPa[idx] += __shfl_xor(sPa[idx], d, 16);
        }
    }
    if (l15 == 0) {
        #pragma unroll
        for (int idx = 0; idx < 8; idx++) {
            const int row = wbase + (idx >> 2) * 16 + lg * 4 + (idx & 3);
            SE[cb * NB + row] = sE[idx];
            SP[cb * NB + row] = sPa[idx];
        }
    }

    // col-sums: combine the 8 waves -> strip[rb] (off-diagonal only)
    if (rb != cb) {
        __syncthreads();
        const int c = tid & 255;
        if (tid < 256) {
            float s = 0.f;
            #pragma unroll
            for (int w2 = 0; w2 < 8; w2++) s += ldsColE[w2][c];
            SE[rb * NB + col0 + c] = s;
        } else {
            float s = 0.f;
            #pragma unroll
            for (int w2 = 0; w2 < 8; w2++) s += ldsColP[w2][c];
            SP[rb * NB + col0 + c] = s;
        }
    }
}

// per-row finalize; 32 blocks of 256 (one 256-row chunk each).
// loss_row = log(se*CEXP + 1e-8) - (spa - n)*INV_T/n   [spa = sum_pos sim]
// Chunk fallback provably dead: CHUNK=256 > NUM_CLASSES=128.
__global__ void k_rows(const int* __restrict__ lab,
                       const float* __restrict__ SE, const float* __restrict__ SP,
                       float* __restrict__ CL, float* __restrict__ CV,
                       int* __restrict__ cnt, float* __restrict__ out) {
    __shared__ int h[128];
    const int t = threadIdx.x;
    if (t < 128) h[t] = 0;
    __syncthreads();
    #pragma unroll
    for (int i = 0; i < 32; i++)
        atomicAdd(&h[lab[t + i * 256]], 1);
    __syncthreads();

    const int row = blockIdx.x * 256 + t;
    float se = 0.f, spa = 0.f;
    #pragma unroll
    for (int s = 0; s < NSTRIP; s++) {
        se  += SE[s * NB + row];
        spa += SP[s * NB + row];
    }
    const int n = h[lab[row]] - 1;
    const float lse = logf(se * CEXP + 1e-8f);
    const bool valid = n > 0;
    float loss = valid ? (lse - (spa - (float)n) * INV_T / (float)n) : 0.f;
    float vf = valid ? 1.f : 0.f;
    #pragma unroll
    for (int d = 32; d; d >>= 1) { loss += __shfl_xor(loss, d, 64); vf += __shfl_xor(vf, d, 64); }
    __shared__ float pl[4], pv[4];
    __shared__ int isLast;
    if ((t & 63) == 0) { pl[t >> 6] = loss; pv[t >> 6] = vf; }
    __syncthreads();
    if (t == 0) {
        CL[blockIdx.x] = pl[0] + pl[1] + pl[2] + pl[3];
        CV[blockIdx.x] = pv[0] + pv[1] + pv[2] + pv[3];
        __threadfence();                       // release CL/CV
        isLast = (atomicAdd(cnt, 1) == 31);
    }
    __syncthreads();
    if (isLast) {
        __threadfence();                       // acquire others' CL/CV
        float lsum = (t < 32) ? CL[t] : 0.f;
        float vsum = (t < 32) ? CV[t] : 0.f;
        #pragma unroll
        for (int d = 32; d; d >>= 1) { lsum += __shfl_xor(lsum, d, 64); vsum += __shfl_xor(vsum, d, 64); }
        if (t == 0) {
            const float mean = lsum / (vsum + 1e-8f);
            out[0] = mean;   // loss (reduction == 'mean')
            out[1] = vsum;   // total_pairs
            out[2] = mean;   // mean_loss
        }
    }
}

extern "C" void kernel_launch(void* const* d_in, const int* in_sizes, int n_in,
                              void* d_out, int out_size, void* d_ws, size_t ws_size,
                              hipStream_t stream) {
    (void)in_sizes; (void)n_in; (void)out_size; (void)ws_size;
    const float* feat = (const float*)d_in[0];
    const int*   lab  = (const int*)d_in[1];
    char* ws = (char*)d_ws;
    __hip_bfloat16* fb = (__hip_bfloat16*)(ws + OFF_FB);
    float* SE = (float*)(ws + OFF_SE);
    float* SP = (float*)(ws + OFF_SP);
    float* CL = (float*)(ws + OFF_CL);
    float* CV = (float*)(ws + OFF_CV);
    int*   cnt = (int*)(ws + OFF_CNT);
    float* out = (float*)d_out;

    hipLaunchKernelGGL(k_norm, dim3(NB / 4), dim3(256), 0, stream, feat, fb, cnt);
    hipLaunchKernelGGL(k_main, dim3(528), dim3(512), 0, stream, fb, lab, SE, SP);
    hipLaunchKernelGGL(k_rows, dim3(NB / 256), dim3(256), 0, stream, lab, SE, SP, CL, CV, cnt, out);
}